// Round 5
// baseline (237.999 us; speedup 1.0000x reference)
//
#include <hip/hip_runtime.h>

#define INF_F 1e20f
#define B_ 16
#define Q_ 64
#define M_ 512
#define F_ 16
#define D_ 512

typedef __attribute__((ext_vector_type(8))) short short8v;
typedef __attribute__((ext_vector_type(4))) float f32x4;

static __device__ __forceinline__ float bits_f(unsigned int u) { return __uint_as_float(u); }

// LDS tile: 64 rows x 32 bf16 (4 granules of 16B) + 16B pad -> pitch 40 shorts (80B).
// Granule-XOR swizzle: phys_granule = granule ^ (row & 3).
static __device__ __forceinline__ int lds_off(int row, int gran) {
    return row * 40 + ((gran ^ (row & 3)) << 3);
}

// split float4 -> hi/lo bf16 uint2 pair (truncated hi, truncated residual lo)
static __device__ __forceinline__ void split4(float4 v, uint2& H, uint2& L) {
    unsigned hx = __float_as_uint(v.x) & 0xffff0000u, hy = __float_as_uint(v.y) & 0xffff0000u;
    unsigned hz = __float_as_uint(v.z) & 0xffff0000u, hw = __float_as_uint(v.w) & 0xffff0000u;
    H.x = (hx >> 16) | hy;
    H.y = (hz >> 16) | hw;
    L.x = (__float_as_uint(v.x - bits_f(hx)) >> 16) | (__float_as_uint(v.y - bits_f(hy)) & 0xffff0000u);
    L.y = (__float_as_uint(v.z - bits_f(hz)) >> 16) | (__float_as_uint(v.w - bits_f(hw)) & 0xffff0000u);
}

static __device__ __forceinline__ void conv_store(short* __restrict__ Hb, short* __restrict__ Lb,
                                                  int row, int c, float4 v) {
    uint2 H, L;
    split4(v, H, L);
    int off = row * 40 + (((c >> 1) ^ (row & 3)) << 3) + ((c & 1) << 2);
    *(uint2*)&Hb[off] = H;
    *(uint2*)&Lb[off] = L;
}

// K0: precompute query hi/lo bf16 in the per-(b,chunk) LDS image order.
// qh/ql element (b,kc,row,sub): from query float4 [b][row][kc*8+sub].
__global__ __launch_bounds__(256) void k_q_split(
    const float* __restrict__ q, uint2* __restrict__ qh, uint2* __restrict__ ql)
{
    int fid = blockIdx.x * 256 + threadIdx.x;       // float4 index over B*Q*128
    float4 v = ((const float4*)q)[fid];
    int col = fid & 127, row = (fid >> 7) & 63, b = fid >> 13;
    int kc = col >> 3, sub = col & 7;
    uint2 H, L;
    split4(v, H, L);
    size_t oidx = ((size_t)(b * 16 + kc) * 512) + row * 8 + sub;
    qh[oidx] = H;
    ql[oidx] = L;
}

// K1: fused attention GEMM (bf16 hi/lo split MFMA) + masks + f-max -> att_qm
//     + softmax(ctx_mask)-weighted f-sum of in_memory -> in_mem_base
//     + plain f-sum of out_memory -> out_mem_sum   (both reduced in-register)
// Block: 256 thr = 4 waves; 4 m (64 B-rows) x 64 q; dbuf LDS, raw barriers
// (no vmcnt drain -> prefetch loads stay in flight across barriers).
__global__ __launch_bounds__(256) void k_att_mfma(
    const uint2* __restrict__ qhg, const uint2* __restrict__ qlg,
    const float* __restrict__ in_mem, const float* __restrict__ out_mem,
    const float* __restrict__ ctx_mask, const float* __restrict__ query_mask,
    float* __restrict__ att_qm, float* __restrict__ in_mem_base,
    float* __restrict__ out_mem_sum)
{
    __shared__ __align__(16) short Qh[2][2560];
    __shared__ __align__(16) short Ql[2][2560];
    __shared__ __align__(16) short Mh[2][2560];
    __shared__ __align__(16) short Ml[2][2560];

    const int bid = blockIdx.x;
    const int b   = bid & 15;             // batch -> XCD pin (b%8) + q/L2 reuse
    const int m0  = (bid >> 4) * 4;       // 4 m per block
    const int t   = threadIdx.x;
    const int w   = t >> 6;               // wave 0..3 -> m = m0 + w
    const int lane = t & 63;
    const int lr  = lane & 15;            // B-row within tile (= f)
    const int lg  = lane >> 4;            // k-granule / q-row group
    const int r0  = (t >> 3) * 2, r1 = r0 + 1;   // staged rows (same m, adjacent f)
    const int scol = t & 7;               // float4 column
    const int f0  = r0 & 15, f1 = f0 + 1;

    // per-thread softmax-over-f weights for this wave's m (= m0 + w)
    float w0, w1;
    {
        const float* cm = ctx_mask + ((size_t)b * M_ + m0 + w) * F_;
        float wv[F_]; float mx = -INF_F;
        #pragma unroll
        for (int f = 0; f < F_; ++f) {
            float cv = cm[f];
            float v = cv - (1.0f - cv) * INF_F;
            wv[f] = v; mx = fmaxf(mx, v);
        }
        float s = 0.f;
        #pragma unroll
        for (int f = 0; f < F_; ++f) { wv[f] = __expf(wv[f] - mx); s += wv[f]; }
        float inv = 1.0f / s;
        w0 = wv[f0] * inv; w1 = wv[f1] * inv;
    }

    const float4* m4 = (const float4*)in_mem;    // [B*M*F][128]
    const float4* o4 = (const float4*)out_mem;
    const size_t mbase = ((size_t)b * M_ + m0) * F_ * 128;
    const size_t qimg  = (size_t)b * 16 * 512;   // uint2 units

    f32x4 acc[4];
    #pragma unroll
    for (int j = 0; j < 4; ++j) acc[j] = (f32x4){0, 0, 0, 0};

    uint2 qhA[2], qlA[2], qhB[2], qlB[2];
    float4 mA[2], oA[2], mB[2], oB[2];

#define LOAD_CHUNK(qh_, ql_, m_, o_, kc) do { int k4 = (kc) * 8;               \
        qh_[0] = qhg[qimg + (size_t)(kc) * 512 + t];                           \
        qh_[1] = qhg[qimg + (size_t)(kc) * 512 + t + 256];                     \
        ql_[0] = qlg[qimg + (size_t)(kc) * 512 + t];                           \
        ql_[1] = qlg[qimg + (size_t)(kc) * 512 + t + 256];                     \
        m_[0] = m4[mbase + (size_t)r0 * 128 + k4 + scol];                      \
        m_[1] = m4[mbase + (size_t)r1 * 128 + k4 + scol];                      \
        o_[0] = o4[mbase + (size_t)r0 * 128 + k4 + scol];                      \
        o_[1] = o4[mbase + (size_t)r1 * 128 + k4 + scol]; } while (0)

#define CONV(qh_, ql_, m_, bi) do {                                            \
        _Pragma("unroll")                                                      \
        for (int i = 0; i < 2; ++i) {                                          \
            int idx = t + i * 256, row = idx >> 3, sub = idx & 7;              \
            int off = row * 40 + (((sub >> 1) ^ (row & 3)) << 3) + ((sub & 1) << 2); \
            *(uint2*)&Qh[bi][off] = qh_[i];                                    \
            *(uint2*)&Ql[bi][off] = ql_[i];                                    \
        }                                                                      \
        conv_store(Mh[bi], Ml[bi], r0, scol, m_[0]);                           \
        conv_store(Mh[bi], Ml[bi], r1, scol, m_[1]); } while (0)

#define BARRIER() do { asm volatile("s_waitcnt lgkmcnt(0)" ::: "memory");      \
        __builtin_amdgcn_s_barrier(); } while (0)

#define MFMA_RED(bi, m_, o_, kc) do {                                          \
        short8v bh = *(const short8v*)&Mh[bi][lds_off(w * 16 + lr, lg)];       \
        short8v bl = *(const short8v*)&Ml[bi][lds_off(w * 16 + lr, lg)];       \
        _Pragma("unroll")                                                      \
        for (int tq = 0; tq < 4; ++tq) {                                       \
            short8v ah = *(const short8v*)&Qh[bi][lds_off(tq * 16 + lr, lg)];  \
            short8v al = *(const short8v*)&Ql[bi][lds_off(tq * 16 + lr, lg)];  \
            acc[tq] = __builtin_amdgcn_mfma_f32_16x16x32_bf16(ah, bh, acc[tq], 0, 0, 0); \
            acc[tq] = __builtin_amdgcn_mfma_f32_16x16x32_bf16(ah, bl, acc[tq], 0, 0, 0); \
            acc[tq] = __builtin_amdgcn_mfma_f32_16x16x32_bf16(al, bh, acc[tq], 0, 0, 0); \
        }                                                                      \
        float4 pin, pout;                                                      \
        pin.x = w0 * m_[0].x + w1 * m_[1].x;  pin.y = w0 * m_[0].y + w1 * m_[1].y; \
        pin.z = w0 * m_[0].z + w1 * m_[1].z;  pin.w = w0 * m_[0].w + w1 * m_[1].w; \
        pout.x = o_[0].x + o_[1].x;  pout.y = o_[0].y + o_[1].y;               \
        pout.z = o_[0].z + o_[1].z;  pout.w = o_[0].w + o_[1].w;               \
        _Pragma("unroll")                                                      \
        for (int sh = 8; sh <= 32; sh <<= 1) {                                 \
            pin.x += __shfl_xor(pin.x, sh, 64);  pin.y += __shfl_xor(pin.y, sh, 64);  \
            pin.z += __shfl_xor(pin.z, sh, 64);  pin.w += __shfl_xor(pin.w, sh, 64);  \
            pout.x += __shfl_xor(pout.x, sh, 64); pout.y += __shfl_xor(pout.y, sh, 64); \
            pout.z += __shfl_xor(pout.z, sh, 64); pout.w += __shfl_xor(pout.w, sh, 64); \
        }                                                                      \
        if (lane < 8) {                                                        \
            size_t oi = ((size_t)b * M_ + m0 + w) * 128 + (kc) * 8 + lane;     \
            ((float4*)in_mem_base)[oi] = pin;                                  \
            ((float4*)out_mem_sum)[oi] = pout;                                 \
        } } while (0)

    LOAD_CHUNK(qhA, qlA, mA, oA, 0);
    #pragma unroll
    for (int it = 0; it < 8; ++it) {
        int kc0 = 2 * it, kc1 = 2 * it + 1;
        LOAD_CHUNK(qhB, qlB, mB, oB, kc1);     // stays in flight across barrier
        CONV(qhA, qlA, mA, 0);
        BARRIER();
        MFMA_RED(0, mA, oA, kc0);
        if (it < 7) LOAD_CHUNK(qhA, qlA, mA, oA, kc0 + 2);
        CONV(qhB, qlB, mB, 1);
        BARRIER();
        MFMA_RED(1, mB, oB, kc1);
    }

    // masks + max over f (16-lane groups), write att_qm; wave w owns m = m0+w
    {
        int m = m0 + w;
        float cmv = ctx_mask[((size_t)b * M_ + m) * F_ + lr];
        #pragma unroll
        for (int tq = 0; tq < 4; ++tq) {
            #pragma unroll
            for (int rg = 0; rg < 4; ++rg) {
                int q = tq * 16 + lg * 4 + rg;
                float qmv = query_mask[b * Q_ + q];
                float v = acc[tq][rg];
                v = cmv * v - (1.0f - cmv) * INF_F;
                v = qmv * v - (1.0f - qmv) * INF_F;
                #pragma unroll
                for (int sh = 1; sh < 16; sh <<= 1) v = fmaxf(v, __shfl_xor(v, sh, 64));
                if (lr == 0)
                    att_qm[((size_t)b * Q_ + q) * M_ + m] = v;
            }
        }
    }
#undef LOAD_CHUNK
#undef CONV
#undef BARRIER
#undef MFMA_RED
}

// K2: softmax over M (in-block) + new_query = query + probs @ out_mem_sum
__global__ __launch_bounds__(128) void k_new_query(
    const float* __restrict__ att, const float* __restrict__ query,
    const float* __restrict__ out_sum, float* __restrict__ new_q)
{
    __shared__ float P[8][512];
    int bid = blockIdx.x;
    int b = bid & 15, qc = bid >> 4;
    int t = threadIdx.x;
    {
        int qi = t >> 4, l16 = t & 15;
        const float* row = att + ((size_t)b * Q_ + qc * 8 + qi) * M_;
        float vals[32]; float mx = -INF_F;
        #pragma unroll
        for (int i = 0; i < 32; ++i) { vals[i] = row[l16 + i * 16]; mx = fmaxf(mx, vals[i]); }
        #pragma unroll
        for (int s = 1; s < 16; s <<= 1) mx = fmaxf(mx, __shfl_xor(mx, s, 64));
        float sm = 0.f;
        #pragma unroll
        for (int i = 0; i < 32; ++i) { vals[i] = __expf(vals[i] - mx); sm += vals[i]; }
        #pragma unroll
        for (int s = 1; s < 16; s <<= 1) sm += __shfl_xor(sm, s, 64);
        float inv = 1.0f / sm;
        #pragma unroll
        for (int i = 0; i < 32; ++i) P[qi][l16 + i * 16] = vals[i] * inv;
    }
    __syncthreads();
    int c = t;
    const float4* o4 = (const float4*)out_sum + (size_t)b * M_ * 128 + c;
    const float4* q4 = (const float4*)query + ((size_t)b * Q_ + qc * 8) * 128 + c;
    float4 acc[8];
    #pragma unroll
    for (int qi = 0; qi < 8; ++qi) acc[qi] = q4[(size_t)qi * 128];
    for (int mm = 0; mm < M_; mm += 4) {
        float4 o0 = o4[(size_t)(mm + 0) * 128];
        float4 o1 = o4[(size_t)(mm + 1) * 128];
        float4 o2 = o4[(size_t)(mm + 2) * 128];
        float4 o3 = o4[(size_t)(mm + 3) * 128];
        #pragma unroll
        for (int qi = 0; qi < 8; ++qi) {
            float4 p = *(const float4*)&P[qi][mm];
            acc[qi].x += p.x * o0.x + p.y * o1.x + p.z * o2.x + p.w * o3.x;
            acc[qi].y += p.x * o0.y + p.y * o1.y + p.z * o2.y + p.w * o3.y;
            acc[qi].z += p.x * o0.z + p.y * o1.z + p.z * o2.z + p.w * o3.z;
            acc[qi].w += p.x * o0.w + p.y * o1.w + p.z * o2.w + p.w * o3.w;
        }
    }
    float4* n4 = (float4*)new_q + ((size_t)b * Q_ + qc * 8) * 128 + c;
    #pragma unroll
    for (int qi = 0; qi < 8; ++qi) n4[(size_t)qi * 128] = acc[qi];
}

// K3: softmax over Q (in-block) + in_mem += p2 @ new_query
__global__ __launch_bounds__(128) void k_in_mem(
    const float* __restrict__ att, const float* __restrict__ new_q,
    float* __restrict__ in_mem_io)
{
    __shared__ float P[8][64];
    int bid = blockIdx.x;
    int b = bid & 15, mc = bid >> 4;
    int m0 = mc * 8;
    int t = threadIdx.x;
    {
        int mi = t >> 4, l16 = t & 15;
        float v[4]; float mx = -INF_F;
        #pragma unroll
        for (int i = 0; i < 4; ++i) {
            v[i] = att[((size_t)b * Q_ + l16 + i * 16) * M_ + m0 + mi];
            mx = fmaxf(mx, v[i]);
        }
        #pragma unroll
        for (int s = 1; s < 16; s <<= 1) mx = fmaxf(mx, __shfl_xor(mx, s, 64));
        float sm = 0.f;
        #pragma unroll
        for (int i = 0; i < 4; ++i) { v[i] = __expf(v[i] - mx); sm += v[i]; }
        #pragma unroll
        for (int s = 1; s < 16; s <<= 1) sm += __shfl_xor(sm, s, 64);
        float inv = 1.0f / sm;
        #pragma unroll
        for (int i = 0; i < 4; ++i) P[mi][l16 + i * 16] = v[i] * inv;
    }
    __syncthreads();
    int c = t;
    float4* io = (float4*)in_mem_io + ((size_t)b * M_ + m0) * 128 + c;
    const float4* n4 = (const float4*)new_q + (size_t)b * Q_ * 128 + c;
    float4 acc[8];
    #pragma unroll
    for (int mi = 0; mi < 8; ++mi) acc[mi] = io[(size_t)mi * 128];
    for (int q = 0; q < Q_; q += 4) {
        float4 n0 = n4[(size_t)(q + 0) * 128];
        float4 n1 = n4[(size_t)(q + 1) * 128];
        float4 n2 = n4[(size_t)(q + 2) * 128];
        float4 n3 = n4[(size_t)(q + 3) * 128];
        #pragma unroll
        for (int mi = 0; mi < 8; ++mi) {
            float4 p = *(const float4*)&P[mi][q];
            acc[mi].x += p.x * n0.x + p.y * n1.x + p.z * n2.x + p.w * n3.x;
            acc[mi].y += p.x * n0.y + p.y * n1.y + p.z * n2.y + p.w * n3.y;
            acc[mi].z += p.x * n0.z + p.y * n1.z + p.z * n2.z + p.w * n3.z;
            acc[mi].w += p.x * n0.w + p.y * n1.w + p.z * n2.w + p.w * n3.w;
        }
    }
    #pragma unroll
    for (int mi = 0; mi < 8; ++mi) io[(size_t)mi * 128] = acc[mi];
}

extern "C" void kernel_launch(void* const* d_in, const int* in_sizes, int n_in,
                              void* d_out, int out_size, void* d_ws, size_t ws_size,
                              hipStream_t stream)
{
    const float* query      = (const float*)d_in[0];
    const float* in_mem     = (const float*)d_in[1];
    const float* out_mem    = (const float*)d_in[2];
    const float* ctx_mask   = (const float*)d_in[3];
    const float* query_mask = (const float*)d_in[4];

    float* out = (float*)d_out;
    float* new_q      = out;                             // B*Q*D
    float* in_mem_out = out + (size_t)B_*Q_*D_;          // B*M*D
    float* out_mem_o  = in_mem_out + (size_t)B_*M_*D_;   // B*M*D

    float* ws     = (float*)d_ws;
    float* att_qm = ws;                                  // B*Q*M floats (2 MB)
    uint2* qh     = (uint2*)(ws + (size_t)B_*Q_*M_);     // B*16*512 uint2 (1 MB)
    uint2* ql     = qh + (size_t)B_*16*512;              // 1 MB

    hipLaunchKernelGGL(k_q_split, dim3(B_*Q_*128/256), dim3(256), 0, stream,
                       query, qh, ql);
    hipLaunchKernelGGL(k_att_mfma, dim3((M_/4) * B_), dim3(256), 0, stream,
                       qh, ql, in_mem, out_mem, ctx_mask, query_mask,
                       att_qm, in_mem_out, out_mem_o);
    hipLaunchKernelGGL(k_new_query, dim3(8 * B_), dim3(128), 0, stream,
                       att_qm, query, out_mem_o, new_q);
    hipLaunchKernelGGL(k_in_mem, dim3(64 * B_), dim3(128), 0, stream,
                       att_qm, new_q, in_mem_out);
}